// Round 3
// baseline (4680.169 us; speedup 1.0000x reference)
//
#include <hip/hip_runtime.h>
#include <hip/hip_bf16.h>

#define Bdim 64
#define Sdim 2048
#define Hdim 256

typedef __attribute__((ext_vector_type(8))) short short8;
typedef __attribute__((ext_vector_type(4))) float f32x4;

static __device__ __forceinline__ unsigned short f2bf(float f) {
  union { float f; unsigned int u; } v; v.f = f;
  unsigned int r = v.u + 0x7fffu + ((v.u >> 16) & 1u);  // RNE
  return (unsigned short)(r >> 16);
}
static __device__ __forceinline__ float bf2f(unsigned short u) {
  union { unsigned int u; float f; } v; v.u = ((unsigned int)u) << 16;
  return v.f;
}
static __device__ __forceinline__ float bflo(unsigned int u) {
  union { unsigned int u; float f; } v; v.u = u << 16; return v.f;
}
static __device__ __forceinline__ float bfhi(unsigned int u) {
  union { unsigned int u; float f; } v; v.u = u & 0xffff0000u; return v.f;
}

#if __has_builtin(__builtin_amdgcn_rcpf)
#define FAST_RCP(x) __builtin_amdgcn_rcpf(x)
#else
#define FAST_RCP(x) (1.0f / (x))
#endif

static __device__ __forceinline__ float tanh_fast(float x) {
  float ax = fabsf(x);
  float e = exp2f(ax * -2.8853900817779268f);  // e^{-2ax}
  float r = (1.0f - e) * FAST_RCP(1.0f + e);
  return copysignf(r, x);
}

// ---------------------------------------------------------------------------
// Phase 2: sequential scan — simple correct VALU version, fp32 h output.
// 64 blocks (one batch each) x 256 threads (thread = one hidden unit n).
// W_hh packed bf16 in LDS as wt[k4][n] = W[n][4k4 .. 4k4+3];
// per-lane reads are consecutive (conflict-free), h reads are broadcasts.
// h kept fp32 in LDS; h_t streamed fp32 to hout (the d_out outputs region).
// XW_MODE: 0 = xw bf16 in ws, 1 = xw f32 in ws, 2 = fused (no ws)
// ---------------------------------------------------------------------------
template<int XW_MODE>
__global__ __launch_bounds__(256, 1) void rnn_scan_valu(
    const void* __restrict__ xwp, const float* __restrict__ x,
    const float* __restrict__ Wih, const float* __restrict__ bh,
    const float* __restrict__ Whh,
    float* __restrict__ hout, float* __restrict__ hfin) {
  __shared__ __align__(16) uint2 wt[64][256];   // 128 KiB
  __shared__ __align__(16) float hl[256];
  const int n = threadIdx.x;
  const int b = blockIdx.x;

  // stage W_hh -> LDS (coalesced float2 global reads, bf16 pack, transpose-4)
  {
    const float2* src = (const float2*)Whh;     // 32768 pairs
    unsigned int* w32 = (unsigned int*)wt;
    for (int i = n; i < 32768; i += 256) {
      float2 f = src[i];
      unsigned int u = (unsigned int)f2bf(f.x) | ((unsigned int)f2bf(f.y) << 16);
      int row = i >> 7;        // W row (= output unit), 0..255
      int kk = i & 127;        // k-pair index, k = 2*kk
      int k4 = kk >> 1, half = kk & 1;
      w32[k4 * 512 + row * 2 + half] = u;       // wt[k4][row].{x,y}
    }
  }
  hl[n] = 0.0f;                                  // h0 = 0
  __syncthreads();

  const unsigned short* xh = (const unsigned short*)xwp;
  const float* xf = (const float*)xwp;
  const long base = (long)b * Sdim * Hdim + n;

  float cur = 0.0f;
  if (XW_MODE == 1) cur = xf[base];
  if (XW_MODE == 0) cur = bf2f(xh[base]);

  for (int t = 0; t < Sdim; ++t) {
    const long idx = base + (long)t * Hdim;
    // software-prefetch next timestep's xw (hidden under the k-loop)
    float nxt = 0.0f;
    if (XW_MODE == 1) nxt = (t + 1 < Sdim) ? xf[idx + Hdim] : 0.0f;
    if (XW_MODE == 0) nxt = (t + 1 < Sdim) ? bf2f(xh[idx + Hdim]) : 0.0f;

    float acc;
    if (XW_MODE == 2) {
      const float* xr = x + ((long)b * Sdim + t) * 256;  // broadcast reads (L1)
      const float* wr = Wih + n * 256;
      acc = bh[n];
      for (int k = 0; k < 256; ++k) acc += xr[k] * wr[k];
    } else {
      acc = cur;
    }

#pragma unroll 8
    for (int k4 = 0; k4 < 64; ++k4) {
      uint2 w2 = wt[k4][n];                          // 8B/lane, conflict-free
      float4 h4 = *(const float4*)&hl[k4 * 4];       // same-addr broadcast
      acc += bflo(w2.x) * h4.x + bfhi(w2.x) * h4.y
           + bflo(w2.y) * h4.z + bfhi(w2.y) * h4.w;
    }

    float hv = tanh_fast(acc);
    __syncthreads();                 // all reads of hl done
    hl[n] = hv;
    hout[idx] = hv;                  // fp32, coalesced
    if (t == Sdim - 1) hfin[b * Hdim + n] = hv;
    cur = nxt;
    __syncthreads();                 // hl update visible before next step
  }
}

// ---------------------------------------------------------------------------
// Phases 1 & 3: out[r,n] = A[r,:] @ W[n,:] + bias[n], A is [131072,256].
// 512 thr (8 waves), 128 rows/block; W fully staged in STATIC LDS (bf16,
// XOR-swizzled). Phase 3 runs IN PLACE over d_out fp32->fp32: each wave reads
// ONLY rows [r0+wv*16, +16) as A and writes exactly those rows; its loads
// precede its stores in the single per-wave instruction stream -> no hazard.
// ---------------------------------------------------------------------------
template<int A_F32, int OUT_F32>
__global__ __launch_bounds__(512, 2) void gemm256(const void* __restrict__ Ap,
                                                  const float* __restrict__ Wf,
                                                  const float* __restrict__ bias,
                                                  void* __restrict__ outp) {
  __shared__ __align__(16) char wl[131072];  // STATIC 128 KiB: W [n][k] bf16, swizzled
  const int tid = threadIdx.x;
  const int lane = tid & 63;
  const int wv = tid >> 6;
  const int l15 = lane & 15;
  const int g = lane >> 4;
  const long r0 = (long)blockIdx.x * 128;

  // stage W -> LDS (f32x4 chunks -> 4 bf16 -> 8B writes)
  for (int i = tid; i < 256 * 64; i += 512) {
    int n = i >> 6;
    int kc = (i & 63) * 4;
    f32x4 c = *(const f32x4*)(Wf + n * 256 + kc);
    unsigned int lo = (unsigned int)f2bf(c[0]) | ((unsigned int)f2bf(c[1]) << 16);
    unsigned int hi = (unsigned int)f2bf(c[2]) | ((unsigned int)f2bf(c[3]) << 16);
    int kb = (kc * 2) ^ ((n & 7) << 4);
    unsigned int* dst = (unsigned int*)(wl + n * 512 + kb);
    dst[0] = lo; dst[1] = hi;
  }
  __syncthreads();

  f32x4 acc[16];
#pragma unroll
  for (int tau = 0; tau < 16; ++tau) {
    float bv = bias[tau * 16 + l15];
    acc[tau][0] = bv; acc[tau][1] = bv; acc[tau][2] = bv; acc[tau][3] = bv;
  }

  const long arow = r0 + wv * 16 + l15;
#pragma unroll
  for (int ks = 0; ks < 8; ++ks) {
    const int k0 = ks * 32 + g * 8;
    short8 a;
    if (A_F32) {
      const f32x4* ap = (const f32x4*)((const float*)Ap + arow * 256 + k0);
      f32x4 x0 = ap[0], x1 = ap[1];
#pragma unroll
      for (int e = 0; e < 4; ++e) { a[e] = (short)f2bf(x0[e]); a[4 + e] = (short)f2bf(x1[e]); }
    } else {
      a = *(const short8*)((const unsigned short*)Ap + arow * 256 + k0);
    }
#pragma unroll
    for (int tau = 0; tau < 16; ++tau) {
      int n = tau * 16 + l15;
      int kb = (k0 * 2) ^ ((n & 7) << 4);
      short8 b = *(const short8*)(wl + n * 512 + kb);
      acc[tau] = __builtin_amdgcn_mfma_f32_16x16x32_bf16(a, b, acc[tau], 0, 0, 0);
    }
  }

  // epilogue: D row m = g*4+e, col n = tau*16+l15  (verified C/D layout)
#pragma unroll
  for (int tau = 0; tau < 16; ++tau) {
    int n = tau * 16 + l15;
#pragma unroll
    for (int e = 0; e < 4; ++e) {
      long row = r0 + wv * 16 + g * 4 + e;
      if (OUT_F32) ((float*)outp)[row * 256 + n] = acc[tau][e];
      else         ((unsigned short*)outp)[row * 256 + n] = f2bf(acc[tau][e]);
    }
  }
}

extern "C" void kernel_launch(void* const* d_in, const int* in_sizes, int n_in,
                              void* d_out, int out_size, void* d_ws, size_t ws_size,
                              hipStream_t stream) {
  const float* x    = (const float*)d_in[0];
  const float* W_ih = (const float*)d_in[1];
  const float* W_hh = (const float*)d_in[2];
  const float* b_h  = (const float*)d_in[3];
  const float* W_ho = (const float*)d_in[4];
  const float* b_o  = (const float*)d_in[5];
  float* out  = (float*)d_out;                              // fp32 output (= reference dtype)
  float* hout = out;                                        // h_t (fp32) lives in outputs region
  float* hfin = out + (size_t)Bdim * Sdim * Hdim;           // h_final slot

  const int gblocks = (Bdim * Sdim) / 128;                  // 1024
  const size_t need32 = (size_t)Bdim * Sdim * Hdim * 4;     // 128 MiB
  const size_t need16 = need32 / 2;                         //  64 MiB

  if (ws_size >= need32) {
    gemm256<1, 1><<<gblocks, 512, 0, stream>>>(x, W_ih, b_h, d_ws);       // phase 1 (f32 xw)
    rnn_scan_valu<1><<<Bdim, 256, 0, stream>>>(d_ws, x, W_ih, b_h, W_hh, hout, hfin);
  } else if (ws_size >= need16) {
    gemm256<1, 0><<<gblocks, 512, 0, stream>>>(x, W_ih, b_h, d_ws);       // phase 1 (bf16 xw)
    rnn_scan_valu<0><<<Bdim, 256, 0, stream>>>(d_ws, x, W_ih, b_h, W_hh, hout, hfin);
  } else {
    rnn_scan_valu<2><<<Bdim, 256, 0, stream>>>(nullptr, x, W_ih, b_h, W_hh, hout, hfin);
  }
  // phase 3: in-place fp32 h -> fp32 outputs
  gemm256<1, 1><<<gblocks, 512, 0, stream>>>(hout, W_ho, b_o, out);
}

// Round 4
// 2164.881 us; speedup vs baseline: 2.1619x; 2.1619x over previous
//
#include <hip/hip_runtime.h>
#include <hip/hip_bf16.h>

#define Bdim 64
#define Sdim 2048
#define Hdim 256

typedef __attribute__((ext_vector_type(8))) short short8;
typedef __attribute__((ext_vector_type(4))) float f32x4;

static __device__ __forceinline__ unsigned short f2bf(float f) {
  union { float f; unsigned int u; } v; v.f = f;
  unsigned int r = v.u + 0x7fffu + ((v.u >> 16) & 1u);  // RNE
  return (unsigned short)(r >> 16);
}
static __device__ __forceinline__ float bf2f(unsigned short u) {
  union { unsigned int u; float f; } v; v.u = ((unsigned int)u) << 16;
  return v.f;
}
static __device__ __forceinline__ float bflo(unsigned int u) {
  union { unsigned int u; float f; } v; v.u = u << 16; return v.f;
}
static __device__ __forceinline__ float bfhi(unsigned int u) {
  union { unsigned int u; float f; } v; v.u = u & 0xffff0000u; return v.f;
}

#if __has_builtin(__builtin_amdgcn_rcpf)
#define FAST_RCP(x) __builtin_amdgcn_rcpf(x)
#else
#define FAST_RCP(x) (1.0f / (x))
#endif

static __device__ __forceinline__ float tanh_fast(float x) {
  float ax = fabsf(x);
  float e = exp2f(ax * -2.8853900817779268f);  // e^{-2ax}
  float r = (1.0f - e) * FAST_RCP(1.0f + e);
  return copysignf(r, x);
}

// ---------------------------------------------------------------------------
// Phase 2: sequential scan, MFMA version. 4 blocks x 512 threads (8 waves);
// block = 16 batches. Per step: h_next[16x256] = tanh(xw_t + h[16x256] @ W_hh^T).
// W_hh held in per-wave register B-frags (wave wv owns cols wv*32..+31, 64 VGPR);
// h double-buffered bf16 in LDS, XOR-swizzled exactly like gemm256's verified
// scheme; xw prefetched 1 step ahead; ONE barrier per step; h_t streamed fp32
// to hout (= d_out outputs region), h_final written at t=S-1.
// XW_F32: 1 = xw f32 in ws, 0 = xw bf16 in ws.
// ---------------------------------------------------------------------------
template<int XW_F32>
__global__ __launch_bounds__(512, 1) void rnn_scan_mfma(
    const void* __restrict__ xwp, const float* __restrict__ Whh,
    float* __restrict__ hout, float* __restrict__ hfin) {
  __shared__ __align__(16) unsigned short hbuf[2][16 * 256];  // 16 KiB
  const int tid = threadIdx.x;
  const int lane = tid & 63;
  const int wv = tid >> 6;     // wave 0..7 -> owns N-cols wv*32..wv*32+31
  const int l15 = lane & 15;
  const int g = lane >> 4;     // 0..3
  const int bs = blockIdx.x * 16;

  for (int i = tid; i < 16 * 256; i += 512) hbuf[0][i] = 0;  // h0 = 0

  // B-frags: lane (l15,g) holds W_hh[n][k] for n = wv*32+tau*16+l15,
  // k = ks*32+g*8+e  — identical packing to gemm256's verified B operand.
  short8 bfrag[2][8];
#pragma unroll
  for (int tau = 0; tau < 2; ++tau) {
    int n = wv * 32 + tau * 16 + l15;
#pragma unroll
    for (int ks = 0; ks < 8; ++ks) {
      int k0 = ks * 32 + g * 8;
      const float* p = Whh + n * 256 + k0;
      short8 v;
#pragma unroll
      for (int e = 0; e < 8; ++e) v[e] = (short)f2bf(p[e]);
      bfrag[tau][ks] = v;
    }
  }

  // A-frag LDS byte offsets: row m=l15, kbyte = (ks*64+g*16) ^ ((m&7)<<4)
  int aroff[8];
#pragma unroll
  for (int ks = 0; ks < 8; ++ks)
    aroff[ks] = l15 * 512 + ((ks * 64 + g * 16) ^ ((l15 & 7) << 4));

  // Output coords: row m = g*4+e, col n = wv*32+tau*16+l15 (verified C/D layout)
  long base[2][4];   // global: (bs+m)*S*H + n
  int woff[2][4];    // LDS bf16 write: m*512 + (2n ^ ((m&7)<<4))
  int fidx[2][4];    // h_final: (bs+m)*H + n
#pragma unroll
  for (int tau = 0; tau < 2; ++tau) {
#pragma unroll
    for (int e = 0; e < 4; ++e) {
      int m = g * 4 + e;
      int n = wv * 32 + tau * 16 + l15;
      base[tau][e] = ((long)(bs + m) * Sdim) * Hdim + n;
      woff[tau][e] = m * 512 + ((n * 2) ^ ((m & 7) << 4));
      fidx[tau][e] = (bs + m) * Hdim + n;
    }
  }

  const float* xwf = (const float*)xwp;
  const unsigned short* xwh = (const unsigned short*)xwp;

  float cur[2][4];
#pragma unroll
  for (int tau = 0; tau < 2; ++tau)
#pragma unroll
    for (int e = 0; e < 4; ++e)
      cur[tau][e] = XW_F32 ? xwf[base[tau][e]] : bf2f(xwh[base[tau][e]]);

  __syncthreads();

  int cb = 0;
  for (int t = 0; t < Sdim; ++t) {
    // prefetch xw for t+1 (hidden under this step's MFMA+LDS)
    const int tn = (t + 1 < Sdim) ? t + 1 : t;
    float nxt[2][4];
#pragma unroll
    for (int tau = 0; tau < 2; ++tau)
#pragma unroll
      for (int e = 0; e < 4; ++e)
        nxt[tau][e] = XW_F32 ? xwf[base[tau][e] + (long)tn * Hdim]
                             : bf2f(xwh[base[tau][e] + (long)tn * Hdim]);

    f32x4 acc0, acc1;  // C-init = xw_t (folded add)
#pragma unroll
    for (int e = 0; e < 4; ++e) { acc0[e] = cur[0][e]; acc1[e] = cur[1][e]; }

    const char* hb = (const char*)hbuf[cb];
#pragma unroll
    for (int ks = 0; ks < 8; ++ks) {
      short8 a = *(const short8*)(hb + aroff[ks]);
      acc0 = __builtin_amdgcn_mfma_f32_16x16x32_bf16(a, bfrag[0][ks], acc0, 0, 0, 0);
      acc1 = __builtin_amdgcn_mfma_f32_16x16x32_bf16(a, bfrag[1][ks], acc1, 0, 0, 0);
    }

    char* hn = (char*)hbuf[cb ^ 1];
#pragma unroll
    for (int tau = 0; tau < 2; ++tau) {
#pragma unroll
      for (int e = 0; e < 4; ++e) {
        float v = tanh_fast(tau == 0 ? acc0[e] : acc1[e]);
        *(unsigned short*)(hn + woff[tau][e]) = f2bf(v);   // next-step A operand
        hout[base[tau][e] + (long)t * Hdim] = v;           // fp32 for phase 3
        if (t == Sdim - 1) hfin[fidx[tau][e]] = v;
      }
    }
#pragma unroll
    for (int tau = 0; tau < 2; ++tau)
#pragma unroll
      for (int e = 0; e < 4; ++e) cur[tau][e] = nxt[tau][e];
    cb ^= 1;
    __syncthreads();  // single barrier per step (double-buffered h)
  }
}

// ---------------------------------------------------------------------------
// Fallback scan (no workspace): fused VALU version — known-good from round 3.
// ---------------------------------------------------------------------------
__global__ __launch_bounds__(256, 1) void rnn_scan_valu_fused(
    const float* __restrict__ x, const float* __restrict__ Wih,
    const float* __restrict__ bh, const float* __restrict__ Whh,
    float* __restrict__ hout, float* __restrict__ hfin) {
  __shared__ __align__(16) uint2 wt[64][256];
  __shared__ __align__(16) float hl[256];
  const int n = threadIdx.x;
  const int b = blockIdx.x;
  {
    const float2* src = (const float2*)Whh;
    unsigned int* w32 = (unsigned int*)wt;
    for (int i = n; i < 32768; i += 256) {
      float2 f = src[i];
      unsigned int u = (unsigned int)f2bf(f.x) | ((unsigned int)f2bf(f.y) << 16);
      int row = i >> 7, kk = i & 127, k4 = kk >> 1, half = kk & 1;
      w32[k4 * 512 + row * 2 + half] = u;
    }
  }
  hl[n] = 0.0f;
  __syncthreads();
  const long base = (long)b * Sdim * Hdim + n;
  for (int t = 0; t < Sdim; ++t) {
    const float* xr = x + ((long)b * Sdim + t) * 256;
    const float* wr = Wih + n * 256;
    float acc = bh[n];
    for (int k = 0; k < 256; ++k) acc += xr[k] * wr[k];
#pragma unroll 8
    for (int k4 = 0; k4 < 64; ++k4) {
      uint2 w2 = wt[k4][n];
      float4 h4 = *(const float4*)&hl[k4 * 4];
      acc += bflo(w2.x) * h4.x + bfhi(w2.x) * h4.y
           + bflo(w2.y) * h4.z + bfhi(w2.y) * h4.w;
    }
    float hv = tanh_fast(acc);
    __syncthreads();
    hl[n] = hv;
    hout[base + (long)t * Hdim] = hv;
    if (t == Sdim - 1) hfin[b * Hdim + n] = hv;
    __syncthreads();
  }
}

// ---------------------------------------------------------------------------
// Phases 1 & 3: out[r,n] = A[r,:] @ W[n,:] + bias[n], A is [131072,256].
// 512 thr (8 waves), 128 rows/block; W fully staged in STATIC LDS (bf16,
// XOR-swizzled). Phase 3 runs IN PLACE over d_out fp32->fp32 (each wave reads
// only the 16 rows it later writes; loads precede stores per-wave).
// ---------------------------------------------------------------------------
template<int A_F32, int OUT_F32>
__global__ __launch_bounds__(512, 2) void gemm256(const void* __restrict__ Ap,
                                                  const float* __restrict__ Wf,
                                                  const float* __restrict__ bias,
                                                  void* __restrict__ outp) {
  __shared__ __align__(16) char wl[131072];
  const int tid = threadIdx.x;
  const int lane = tid & 63;
  const int wv = tid >> 6;
  const int l15 = lane & 15;
  const int g = lane >> 4;
  const long r0 = (long)blockIdx.x * 128;

  for (int i = tid; i < 256 * 64; i += 512) {
    int n = i >> 6;
    int kc = (i & 63) * 4;
    f32x4 c = *(const f32x4*)(Wf + n * 256 + kc);
    unsigned int lo = (unsigned int)f2bf(c[0]) | ((unsigned int)f2bf(c[1]) << 16);
    unsigned int hi = (unsigned int)f2bf(c[2]) | ((unsigned int)f2bf(c[3]) << 16);
    int kb = (kc * 2) ^ ((n & 7) << 4);
    unsigned int* dst = (unsigned int*)(wl + n * 512 + kb);
    dst[0] = lo; dst[1] = hi;
  }
  __syncthreads();

  f32x4 acc[16];
#pragma unroll
  for (int tau = 0; tau < 16; ++tau) {
    float bv = bias[tau * 16 + l15];
    acc[tau][0] = bv; acc[tau][1] = bv; acc[tau][2] = bv; acc[tau][3] = bv;
  }

  const long arow = r0 + wv * 16 + l15;
#pragma unroll
  for (int ks = 0; ks < 8; ++ks) {
    const int k0 = ks * 32 + g * 8;
    short8 a;
    if (A_F32) {
      const f32x4* ap = (const f32x4*)((const float*)Ap + arow * 256 + k0);
      f32x4 x0 = ap[0], x1 = ap[1];
#pragma unroll
      for (int e = 0; e < 4; ++e) { a[e] = (short)f2bf(x0[e]); a[4 + e] = (short)f2bf(x1[e]); }
    } else {
      a = *(const short8*)((const unsigned short*)Ap + arow * 256 + k0);
    }
#pragma unroll
    for (int tau = 0; tau < 16; ++tau) {
      int n = tau * 16 + l15;
      int kb = (k0 * 2) ^ ((n & 7) << 4);
      short8 b = *(const short8*)(wl + n * 512 + kb);
      acc[tau] = __builtin_amdgcn_mfma_f32_16x16x32_bf16(a, b, acc[tau], 0, 0, 0);
    }
  }

#pragma unroll
  for (int tau = 0; tau < 16; ++tau) {
    int n = tau * 16 + l15;
#pragma unroll
    for (int e = 0; e < 4; ++e) {
      long row = r0 + wv * 16 + g * 4 + e;
      if (OUT_F32) ((float*)outp)[row * 256 + n] = acc[tau][e];
      else         ((unsigned short*)outp)[row * 256 + n] = f2bf(acc[tau][e]);
    }
  }
}

extern "C" void kernel_launch(void* const* d_in, const int* in_sizes, int n_in,
                              void* d_out, int out_size, void* d_ws, size_t ws_size,
                              hipStream_t stream) {
  const float* x    = (const float*)d_in[0];
  const float* W_ih = (const float*)d_in[1];
  const float* W_hh = (const float*)d_in[2];
  const float* b_h  = (const float*)d_in[3];
  const float* W_ho = (const float*)d_in[4];
  const float* b_o  = (const float*)d_in[5];
  float* out  = (float*)d_out;                              // fp32 output
  float* hout = out;                                        // h_t lives in outputs region
  float* hfin = out + (size_t)Bdim * Sdim * Hdim;           // h_final slot

  const int gblocks = (Bdim * Sdim) / 128;                  // 1024
  const size_t need32 = (size_t)Bdim * Sdim * Hdim * 4;     // 128 MiB
  const size_t need16 = need32 / 2;                         //  64 MiB

  if (ws_size >= need32) {
    gemm256<1, 1><<<gblocks, 512, 0, stream>>>(x, W_ih, b_h, d_ws);       // phase 1 (f32 xw)
    rnn_scan_mfma<1><<<4, 512, 0, stream>>>(d_ws, W_hh, hout, hfin);      // phase 2
  } else if (ws_size >= need16) {
    gemm256<1, 0><<<gblocks, 512, 0, stream>>>(x, W_ih, b_h, d_ws);       // phase 1 (bf16 xw)
    rnn_scan_mfma<0><<<4, 512, 0, stream>>>(d_ws, W_hh, hout, hfin);
  } else {
    rnn_scan_valu_fused<<<Bdim, 256, 0, stream>>>(x, W_ih, b_h, W_hh, hout, hfin);
  }
  // phase 3: in-place fp32 h -> fp32 outputs
  gemm256<1, 1><<<gblocks, 512, 0, stream>>>(hout, W_ho, b_o, out);
}

// Round 5
// 2134.741 us; speedup vs baseline: 2.1924x; 1.0141x over previous
//
#include <hip/hip_runtime.h>
#include <hip/hip_bf16.h>

#define Bdim 64
#define Sdim 2048
#define Hdim 256

typedef __attribute__((ext_vector_type(8))) short short8;
typedef __attribute__((ext_vector_type(4))) float f32x4;

static __device__ __forceinline__ unsigned short f2bf(float f) {
  union { float f; unsigned int u; } v; v.f = f;
  unsigned int r = v.u + 0x7fffu + ((v.u >> 16) & 1u);  // RNE
  return (unsigned short)(r >> 16);
}
static __device__ __forceinline__ float bf2f(unsigned short u) {
  union { unsigned int u; float f; } v; v.u = ((unsigned int)u) << 16;
  return v.f;
}
static __device__ __forceinline__ float bflo(unsigned int u) {
  union { unsigned int u; float f; } v; v.u = u << 16; return v.f;
}
static __device__ __forceinline__ float bfhi(unsigned int u) {
  union { unsigned int u; float f; } v; v.u = u & 0xffff0000u; return v.f;
}

#if __has_builtin(__builtin_amdgcn_rcpf)
#define FAST_RCP(x) __builtin_amdgcn_rcpf(x)
#else
#define FAST_RCP(x) (1.0f / (x))
#endif

static __device__ __forceinline__ float tanh_fast(float x) {
  float ax = fabsf(x);
  float e = exp2f(ax * -2.8853900817779268f);  // e^{-2ax}
  float r = (1.0f - e) * FAST_RCP(1.0f + e);
  return copysignf(r, x);
}

// ---------------------------------------------------------------------------
// Phase 2: sequential scan, MFMA version. 4 blocks x 512 threads (8 waves);
// block = 16 batches. Per step: h_next[16x256] = tanh(xw_t + h[16x256] @ W_hh^T).
// W_hh in per-wave register B-frags; h double-buffered bf16 in LDS (verified
// XOR swizzle); xw prefetched DEPTH-2 into two register buffers (unroll-by-2,
// no cur=nxt copies); per-step sync = lgkmcnt(0)+raw s_barrier ONLY (no vmcnt
// drain — xw loads and hout stores stay in flight across barriers).
// ---------------------------------------------------------------------------
template<int XW_F32>
__global__ __launch_bounds__(512, 1) void rnn_scan_mfma(
    const void* __restrict__ xwp, const float* __restrict__ Whh,
    float* __restrict__ hout, float* __restrict__ hfin) {
  __shared__ __align__(16) unsigned short hbuf[2][16 * 256];  // 16 KiB
  const int tid = threadIdx.x;
  const int lane = tid & 63;
  const int wv = tid >> 6;     // wave 0..7 -> owns N-cols wv*32..wv*32+31
  const int l15 = lane & 15;
  const int g = lane >> 4;     // 0..3
  const int bs = blockIdx.x * 16;

  for (int i = tid; i < 16 * 256; i += 512) hbuf[0][i] = 0;  // h0 = 0

  // B-frags: lane (l15,g) holds W_hh[n][k] for n = wv*32+tau*16+l15,
  // k = ks*32+g*8+e  (identical packing to gemm256's verified B operand).
  short8 bfrag[2][8];
#pragma unroll
  for (int tau = 0; tau < 2; ++tau) {
    int n = wv * 32 + tau * 16 + l15;
#pragma unroll
    for (int ks = 0; ks < 8; ++ks) {
      int k0 = ks * 32 + g * 8;
      const float* p = Whh + n * 256 + k0;
      short8 v;
#pragma unroll
      for (int e = 0; e < 8; ++e) v[e] = (short)f2bf(p[e]);
      bfrag[tau][ks] = v;
    }
  }

  // A-frag LDS byte offsets: row m=l15, kbyte = (ks*64+g*16) ^ ((m&7)<<4)
  int aroff[8];
#pragma unroll
  for (int ks = 0; ks < 8; ++ks)
    aroff[ks] = l15 * 512 + ((ks * 64 + g * 16) ^ ((l15 & 7) << 4));

  // Output coords: row m = g*4+e, col n = wv*32+tau*16+l15 (verified C/D layout)
  long base[2][4];   // global: (bs+m)*S*H + n
  int woff[2][4];    // LDS bf16 write: m*512 + (2n ^ ((m&7)<<4))
  int fidx[2][4];    // h_final: (bs+m)*H + n
#pragma unroll
  for (int tau = 0; tau < 2; ++tau) {
#pragma unroll
    for (int e = 0; e < 4; ++e) {
      int m = g * 4 + e;
      int n = wv * 32 + tau * 16 + l15;
      base[tau][e] = ((long)(bs + m) * Sdim) * Hdim + n;
      woff[tau][e] = m * 512 + ((n * 2) ^ ((m & 7) << 4));
      fidx[tau][e] = (bs + m) * Hdim + n;
    }
  }

  const float* xwf = (const float*)xwp;
  const unsigned short* xwh = (const unsigned short*)xwp;

  // depth-2 xw prefetch buffers: xwA = step t (even), xwB = step t+1 (odd)
  float xwA[2][4], xwB[2][4];
#pragma unroll
  for (int tau = 0; tau < 2; ++tau)
#pragma unroll
    for (int e = 0; e < 4; ++e) {
      xwA[tau][e] = XW_F32 ? xwf[base[tau][e]] : bf2f(xwh[base[tau][e]]);
      xwB[tau][e] = XW_F32 ? xwf[base[tau][e] + Hdim] : bf2f(xwh[base[tau][e] + Hdim]);
    }

  __syncthreads();  // h0 init + (full drain once, outside the loop)

  int cb = 0;
  auto step = [&](int tc, float (&buf)[2][4]) {
    f32x4 acc0, acc1;  // C-init = xw_tc (folded add)
#pragma unroll
    for (int e = 0; e < 4; ++e) { acc0[e] = buf[0][e]; acc1[e] = buf[1][e]; }

    // refill this buffer with xw for tc+2 (consumed two steps from now)
    const int tn = (tc + 2 < Sdim) ? tc + 2 : Sdim - 1;
#pragma unroll
    for (int tau = 0; tau < 2; ++tau)
#pragma unroll
      for (int e = 0; e < 4; ++e)
        buf[tau][e] = XW_F32 ? xwf[base[tau][e] + (long)tn * Hdim]
                             : bf2f(xwh[base[tau][e] + (long)tn * Hdim]);

    const char* hb = (const char*)hbuf[cb];
#pragma unroll
    for (int ks = 0; ks < 8; ++ks) {
      short8 a = *(const short8*)(hb + aroff[ks]);
      acc0 = __builtin_amdgcn_mfma_f32_16x16x32_bf16(a, bfrag[0][ks], acc0, 0, 0, 0);
      acc1 = __builtin_amdgcn_mfma_f32_16x16x32_bf16(a, bfrag[1][ks], acc1, 0, 0, 0);
    }

    char* hn = (char*)hbuf[cb ^ 1];
#pragma unroll
    for (int tau = 0; tau < 2; ++tau) {
#pragma unroll
      for (int e = 0; e < 4; ++e) {
        float v = tanh_fast(tau == 0 ? acc0[e] : acc1[e]);
        *(unsigned short*)(hn + woff[tau][e]) = f2bf(v);   // next-step A operand
        hout[base[tau][e] + (long)tc * Hdim] = v;          // fp32 for phase 3
        if (tc == Sdim - 1) hfin[fidx[tau][e]] = v;
      }
    }

    // barrier WITHOUT vmcnt drain: only LDS ops must complete/order here.
    __builtin_amdgcn_sched_barrier(0);
    asm volatile("s_waitcnt lgkmcnt(0)" ::: "memory");
    __builtin_amdgcn_s_barrier();
    __builtin_amdgcn_sched_barrier(0);
    cb ^= 1;
  };

  for (int t = 0; t < Sdim; t += 2) {
    step(t, xwA);
    step(t + 1, xwB);
  }
}

// ---------------------------------------------------------------------------
// Fallback scan (no workspace): fused VALU version — known-good from round 3.
// ---------------------------------------------------------------------------
__global__ __launch_bounds__(256, 1) void rnn_scan_valu_fused(
    const float* __restrict__ x, const float* __restrict__ Wih,
    const float* __restrict__ bh, const float* __restrict__ Whh,
    float* __restrict__ hout, float* __restrict__ hfin) {
  __shared__ __align__(16) uint2 wt[64][256];
  __shared__ __align__(16) float hl[256];
  const int n = threadIdx.x;
  const int b = blockIdx.x;
  {
    const float2* src = (const float2*)Whh;
    unsigned int* w32 = (unsigned int*)wt;
    for (int i = n; i < 32768; i += 256) {
      float2 f = src[i];
      unsigned int u = (unsigned int)f2bf(f.x) | ((unsigned int)f2bf(f.y) << 16);
      int row = i >> 7, kk = i & 127, k4 = kk >> 1, half = kk & 1;
      w32[k4 * 512 + row * 2 + half] = u;
    }
  }
  hl[n] = 0.0f;
  __syncthreads();
  const long base = (long)b * Sdim * Hdim + n;
  for (int t = 0; t < Sdim; ++t) {
    const float* xr = x + ((long)b * Sdim + t) * 256;
    const float* wr = Wih + n * 256;
    float acc = bh[n];
    for (int k = 0; k < 256; ++k) acc += xr[k] * wr[k];
#pragma unroll 8
    for (int k4 = 0; k4 < 64; ++k4) {
      uint2 w2 = wt[k4][n];
      float4 h4 = *(const float4*)&hl[k4 * 4];
      acc += bflo(w2.x) * h4.x + bfhi(w2.x) * h4.y
           + bflo(w2.y) * h4.z + bfhi(w2.y) * h4.w;
    }
    float hv = tanh_fast(acc);
    __syncthreads();
    hl[n] = hv;
    hout[base + (long)t * Hdim] = hv;
    if (t == Sdim - 1) hfin[b * Hdim + n] = hv;
    __syncthreads();
  }
}

// ---------------------------------------------------------------------------
// Phases 1 & 3: out[r,n] = A[r,:] @ W[n,:] + bias[n], A is [131072,256].
// 512 thr (8 waves), 128 rows/block; W fully staged in STATIC LDS (bf16,
// XOR-swizzled). Phase 3 runs IN PLACE over d_out fp32->fp32 (each wave reads
// only the 16 rows it later writes; loads precede stores per-wave).
// ---------------------------------------------------------------------------
template<int A_F32, int OUT_F32>
__global__ __launch_bounds__(512, 2) void gemm256(const void* __restrict__ Ap,
                                                  const float* __restrict__ Wf,
                                                  const float* __restrict__ bias,
                                                  void* __restrict__ outp) {
  __shared__ __align__(16) char wl[131072];
  const int tid = threadIdx.x;
  const int lane = tid & 63;
  const int wv = tid >> 6;
  const int l15 = lane & 15;
  const int g = lane >> 4;
  const long r0 = (long)blockIdx.x * 128;

  for (int i = tid; i < 256 * 64; i += 512) {
    int n = i >> 6;
    int kc = (i & 63) * 4;
    f32x4 c = *(const f32x4*)(Wf + n * 256 + kc);
    unsigned int lo = (unsigned int)f2bf(c[0]) | ((unsigned int)f2bf(c[1]) << 16);
    unsigned int hi = (unsigned int)f2bf(c[2]) | ((unsigned int)f2bf(c[3]) << 16);
    int kb = (kc * 2) ^ ((n & 7) << 4);
    unsigned int* dst = (unsigned int*)(wl + n * 512 + kb);
    dst[0] = lo; dst[1] = hi;
  }
  __syncthreads();

  f32x4 acc[16];
#pragma unroll
  for (int tau = 0; tau < 16; ++tau) {
    float bv = bias[tau * 16 + l15];
    acc[tau][0] = bv; acc[tau][1] = bv; acc[tau][2] = bv; acc[tau][3] = bv;
  }

  const long arow = r0 + wv * 16 + l15;
#pragma unroll
  for (int ks = 0; ks < 8; ++ks) {
    const int k0 = ks * 32 + g * 8;
    short8 a;
    if (A_F32) {
      const f32x4* ap = (const f32x4*)((const float*)Ap + arow * 256 + k0);
      f32x4 x0 = ap[0], x1 = ap[1];
#pragma unroll
      for (int e = 0; e < 4; ++e) { a[e] = (short)f2bf(x0[e]); a[4 + e] = (short)f2bf(x1[e]); }
    } else {
      a = *(const short8*)((const unsigned short*)Ap + arow * 256 + k0);
    }
#pragma unroll
    for (int tau = 0; tau < 16; ++tau) {
      int n = tau * 16 + l15;
      int kb = (k0 * 2) ^ ((n & 7) << 4);
      short8 b = *(const short8*)(wl + n * 512 + kb);
      acc[tau] = __builtin_amdgcn_mfma_f32_16x16x32_bf16(a, b, acc[tau], 0, 0, 0);
    }
  }

#pragma unroll
  for (int tau = 0; tau < 16; ++tau) {
    int n = tau * 16 + l15;
#pragma unroll
    for (int e = 0; e < 4; ++e) {
      long row = r0 + wv * 16 + g * 4 + e;
      if (OUT_F32) ((float*)outp)[row * 256 + n] = acc[tau][e];
      else         ((unsigned short*)outp)[row * 256 + n] = f2bf(acc[tau][e]);
    }
  }
}

extern "C" void kernel_launch(void* const* d_in, const int* in_sizes, int n_in,
                              void* d_out, int out_size, void* d_ws, size_t ws_size,
                              hipStream_t stream) {
  const float* x    = (const float*)d_in[0];
  const float* W_ih = (const float*)d_in[1];
  const float* W_hh = (const float*)d_in[2];
  const float* b_h  = (const float*)d_in[3];
  const float* W_ho = (const float*)d_in[4];
  const float* b_o  = (const float*)d_in[5];
  float* out  = (float*)d_out;                              // fp32 output
  float* hout = out;                                        // h_t lives in outputs region
  float* hfin = out + (size_t)Bdim * Sdim * Hdim;           // h_final slot

  const int gblocks = (Bdim * Sdim) / 128;                  // 1024
  const size_t need32 = (size_t)Bdim * Sdim * Hdim * 4;     // 128 MiB
  const size_t need16 = need32 / 2;                         //  64 MiB

  if (ws_size >= need32) {
    gemm256<1, 1><<<gblocks, 512, 0, stream>>>(x, W_ih, b_h, d_ws);       // phase 1 (f32 xw)
    rnn_scan_mfma<1><<<4, 512, 0, stream>>>(d_ws, W_hh, hout, hfin);      // phase 2
  } else if (ws_size >= need16) {
    gemm256<1, 0><<<gblocks, 512, 0, stream>>>(x, W_ih, b_h, d_ws);       // phase 1 (bf16 xw)
    rnn_scan_mfma<0><<<4, 512, 0, stream>>>(d_ws, W_hh, hout, hfin);
  } else {
    rnn_scan_valu_fused<<<Bdim, 256, 0, stream>>>(x, W_ih, b_h, W_hh, hout, hfin);
  }
  // phase 3: in-place fp32 h -> fp32 outputs
  gemm256<1, 1><<<gblocks, 512, 0, stream>>>(hout, W_ho, b_o, out);
}